// Round 1
// baseline (219.950 us; speedup 1.0000x reference)
//
#include <hip/hip_runtime.h>
#include <stdint.h>

typedef unsigned short u16;
typedef __attribute__((ext_vector_type(8))) short short8;
typedef __attribute__((ext_vector_type(4))) float f32x4;

#define NIMG 32
#define CH   512         // Cin == Cout == 512
#define HH   28
#define WW   28
#define HP   30          // padded
#define WP   30
#define PIX  784         // 28*28
#define KSZ  4608        // 512*9
#define ALPHA_C 0.2f

// ---- async global->LDS, 16B per lane (LDS dest = wave-uniform base + lane*16) ----
__device__ __forceinline__ void gload16(const void* g, void* l) {
  __builtin_amdgcn_global_load_lds((const __attribute__((address_space(1))) void*)g,
                                   (__attribute__((address_space(3))) void*)l, 16, 0, 0);
}

// ---- block (256-thread) sum reduction ----
__device__ __forceinline__ float blocksum256(float v, float* red) {
  v += __shfl_down(v, 32); v += __shfl_down(v, 16); v += __shfl_down(v, 8);
  v += __shfl_down(v, 4);  v += __shfl_down(v, 2);  v += __shfl_down(v, 1);
  const int t = threadIdx.x;
  __syncthreads();                       // protect red[] from previous use
  if ((t & 63) == 0) red[t >> 6] = v;
  __syncthreads();
  return red[0] + red[1] + red[2] + red[3];
}

// ================= weight transform =================
// per output channel o: standardize w (biased std), sign -> bf16 +-1,
// scale[o] = mean|w_std| * gain[o] * ALPHA.  Wt layout: [o][ (kh*3+kw)*512 + ci ]
__global__ __launch_bounds__(256) void wker(const float* __restrict__ w,
                                            const float* __restrict__ gain,
                                            u16* __restrict__ Wt,
                                            float* __restrict__ wsc) {
  __shared__ float sw[KSZ];
  __shared__ float red[4];
  const int o = blockIdx.x;
  const int t = threadIdx.x;
  const float* wo = w + (size_t)o * KSZ;

  float s = 0.f;
  for (int j = t; j < KSZ; j += 256) { float v = wo[j]; sw[j] = v; s += v; }
  const float mean = blocksum256(s, red) * (1.f / 4608.f);

  float s2 = 0.f;
  for (int j = t; j < KSZ; j += 256) { float d = sw[j] - mean; s2 += d * d; }
  const float var  = blocksum256(s2, red) * (1.f / 4608.f);
  const float stdv = sqrtf(var);
  const float scale = 1.0f / sqrtf(4608.0f);
  const float inv = scale / (stdv + 1e-5f);

  float sa = 0.f;
  for (int j = t; j < KSZ; j += 256) {
    float ws = (sw[j] - mean) * inv;
    sa += fabsf(ws);
    u16 u = ws > 0.f ? 0x3F80u : (ws < 0.f ? 0xBF80u : 0u);   // bf16 +-1 / 0
    Wt[(size_t)o * KSZ + (size_t)(j % 9) * CH + (j / 9)] = u; // OIHW -> (kh,kw,ci)
  }
  const float sf = blocksum256(sa, red) * (1.f / 4608.f);
  if (t == 0) wsc[o] = sf * gain[o] * ALPHA_C;
}

// ================= input binarize + NCHW -> padded NHWC bf16 =================
// P[n][hp][wp][ci] = sign(x*BETA + move0_bias), borders pre-zeroed by memset.
__global__ __launch_bounds__(256) void bker(const float* __restrict__ x,
                                            const float* __restrict__ mb0,
                                            u16* __restrict__ P) {
  __shared__ float tile[64][57];         // +pad: stride 57 (coprime w/ 32 banks)
  const int pc = blockIdx.x;             // 14 pixel chunks of 56
  const int cc = blockIdx.y;             // 8 ci chunks of 64
  const int n  = blockIdx.z;
  const int p0 = pc * 56;
  const int ci0 = cc * 64;
  const int t = threadIdx.x;

  const float* xb = x + ((size_t)n * CH + ci0) * PIX + p0;
  for (int i = t; i < 64 * 56; i += 256) {
    int ci = i / 56, p = i - ci * 56;
    tile[ci][p] = xb[(size_t)ci * PIX + p];   // coalesced 56-wide rows
  }
  __syncthreads();
  for (int i = t; i < 56 * 64; i += 256) {
    int p = i >> 6, ci = i & 63;
    float v = tile[ci][p] * 1.0f + mb0[ci0 + ci];   // BETA = 1.0
    u16 u = v > 0.f ? 0x3F80u : (v < 0.f ? 0xBF80u : 0u);
    int pg = p0 + p;
    int h = pg / 28, wq = pg - h * 28;
    P[(((size_t)n * HP + (h + 1)) * WP + (wq + 1)) * CH + ci0 + ci] = u;
  }
}

// ================= binary implicit-GEMM conv + fused epilogue =================
// M=25088 (n,h,w), N=512 (o), K=4608 ((kh,kw),ci). 128x128 tile, BK=64,
// 4 waves (2x2), each wave 4x4 frags of 16x16x32 bf16 MFMA.
__global__ __launch_bounds__(256) void gemm_bin(const u16* __restrict__ P,
                                                const u16* __restrict__ Wt,
                                                const float* __restrict__ wsc,
                                                const float* __restrict__ x,
                                                const float* __restrict__ mb1,
                                                const float* __restrict__ pa,
                                                const float* __restrict__ mb2,
                                                float* __restrict__ out) {
  __shared__ u16 As[128 * 64];   // 16 KB, XOR-swizzled rows
  __shared__ u16 Bs[128 * 64];   // 16 KB

  // bijective XCD swizzle: 784 = 98*8
  const int bid = blockIdx.x;
  const int swz = (bid & 7) * 98 + (bid >> 3);
  const int bm = swz >> 2, bn = swz & 3;
  const int m0 = bm * 128, o0 = bn * 128;

  const int t = threadIdx.x;
  const int lane = t & 63, wid = t >> 6;
  const int wr = wid >> 1, wc = wid & 1;

  // ---- staging address precompute (4 chunks of 16B per thread per tile) ----
  const int c8 = t & 7;                 // 16B chunk within a 128B row
  const int rbase = t >> 3;             // 0..31 ; row = it*32 + rbase
  // pre-swizzled source offset (elements) within a 64-elem K row:
  const int swko = (((c8 * 16) ^ ((rbase & 7) << 4)) >> 1);

  size_t apix[4];
#pragma unroll
  for (int it = 0; it < 4; ++it) {
    int m = m0 + it * 32 + rbase;
    int n = m / PIX;
    int pix = m - n * PIX;
    int h = pix / 28, wq = pix - h * 28;
    // padded base for (kh=0,kw=0); output pixel h reads padded rows h..h+2
    apix[it] = (((size_t)n * HP + h) * WP + wq) * CH + swko;
  }
  const u16* Bbase = Wt + (size_t)(o0 + rbase) * KSZ + swko;

  f32x4 acc[4][4] = {};

  for (int kt = 0; kt < 72; ++kt) {
    const int pos = kt >> 3;                       // kh*3+kw
    const int kh = pos / 3, kw = pos - kh * 3;
    const size_t aoff = ((size_t)(kh * WP + kw)) * CH + (size_t)(kt & 7) * 64;
    const size_t boff = (size_t)kt * 64;

    __syncthreads();                               // LDS reuse guard
#pragma unroll
    for (int it = 0; it < 4; ++it) {
      gload16(P + apix[it] + aoff, (char*)As + it * 4096 + wid * 1024);
      gload16(Bbase + (size_t)it * 32 * KSZ + boff, (char*)Bs + it * 4096 + wid * 1024);
    }
    __syncthreads();                               // compiler drains vmcnt here

    const int kq = lane >> 4;                      // 0..3
    const int rl = lane & 15;
#pragma unroll
    for (int ks = 0; ks < 2; ++ks) {
      short8 a[4], b[4];
      const int kb = ks * 64 + kq * 16;            // byte offset in 128B row
#pragma unroll
      for (int mf = 0; mf < 4; ++mf) {
        int r = wr * 64 + mf * 16 + rl;
        a[mf] = *(const short8*)((const char*)As + r * 128 + (kb ^ ((r & 7) << 4)));
      }
#pragma unroll
      for (int nf = 0; nf < 4; ++nf) {
        int r = wc * 64 + nf * 16 + rl;
        b[nf] = *(const short8*)((const char*)Bs + r * 128 + (kb ^ ((r & 7) << 4)));
      }
#pragma unroll
      for (int mf = 0; mf < 4; ++mf)
#pragma unroll
        for (int nf = 0; nf < 4; ++nf)
          acc[mf][nf] = __builtin_amdgcn_mfma_f32_16x16x32_bf16(a[mf], b[nf], acc[mf][nf], 0, 0, 0);
    }
  }

  // ---- fused epilogue: *wsc + residual + b1 -> PReLU -> + b2 ----
  const int ccol = lane & 15;
  const int rq4 = (lane >> 4) * 4;
#pragma unroll
  for (int nf = 0; nf < 4; ++nf) {
    const int o = o0 + wc * 64 + nf * 16 + ccol;
    const float wv = wsc[o];
    const float b1 = mb1[o];
    const float ap = pa[o];
    const float b2 = mb2[o];
#pragma unroll
    for (int mf = 0; mf < 4; ++mf) {
      const int m = m0 + wr * 64 + mf * 16 + rq4;
      const int n = m / PIX;
      const int pix = m - n * PIX;
      const size_t base = ((size_t)(n * CH + o)) * PIX + pix;  // NCHW fp32
      const float4 r = *reinterpret_cast<const float4*>(x + base);
      const float rv[4] = {r.x, r.y, r.z, r.w};
      float4 ov;
      float* po = &ov.x;
#pragma unroll
      for (int q = 0; q < 4; ++q) {
        float v = acc[mf][nf][q] * wv + rv[q] + b1;
        v = v >= 0.f ? v : ap * v;
        po[q] = v + b2;
      }
      *reinterpret_cast<float4*>(out + base) = ov;
    }
  }
}

extern "C" void kernel_launch(void* const* d_in, const int* in_sizes, int n_in,
                              void* d_out, int out_size, void* d_ws, size_t ws_size,
                              hipStream_t stream) {
  const float* x    = (const float*)d_in[0];
  const float* mb0  = (const float*)d_in[1];
  const float* w    = (const float*)d_in[2];
  const float* gain = (const float*)d_in[3];
  const float* mb1  = (const float*)d_in[4];
  const float* pa   = (const float*)d_in[5];
  const float* mb2  = (const float*)d_in[6];
  float* out = (float*)d_out;

  char* ws = (char*)d_ws;
  const size_t P_BYTES  = (size_t)NIMG * HP * WP * CH * sizeof(u16);  // 29,491,200
  const size_t WT_BYTES = (size_t)CH * KSZ * sizeof(u16);             //  4,718,592
  u16*   P  = (u16*)ws;
  u16*   Wt = (u16*)(ws + P_BYTES);
  float* wv = (float*)(ws + P_BYTES + WT_BYTES);

  hipMemsetAsync(P, 0, P_BYTES, stream);                 // zero halo
  wker<<<512, 256, 0, stream>>>(w, gain, Wt, wv);
  bker<<<dim3(14, 8, NIMG), 256, 0, stream>>>(x, mb0, P);
  gemm_bin<<<784, 256, 0, stream>>>(P, Wt, wv, x, mb1, pa, mb2, out);
}

// Round 2
// 139.711 us; speedup vs baseline: 1.5743x; 1.5743x over previous
//
#include <hip/hip_runtime.h>
#include <stdint.h>

typedef unsigned short u16;
typedef signed char i8t;
typedef __attribute__((ext_vector_type(4))) int i32x4;

#define NIMG 32
#define CH   512         // Cin == Cout == 512
#define HP   30          // padded
#define WP   30
#define PIX  784         // 28*28
#define KSZ  4608        // 512*9
#define ALPHA_C 0.2f
#define NKT  36          // K tiles of 128 (i8)

// ---- async global->LDS, 16B per lane (LDS dest = wave-uniform base + lane*16) ----
__device__ __forceinline__ void gload16(const void* g, void* l) {
  __builtin_amdgcn_global_load_lds((const __attribute__((address_space(1))) void*)g,
                                   (__attribute__((address_space(3))) void*)l, 16, 0, 0);
}

// ---- block (256-thread) sum reduction ----
__device__ __forceinline__ float blocksum256(float v, float* red) {
  v += __shfl_down(v, 32); v += __shfl_down(v, 16); v += __shfl_down(v, 8);
  v += __shfl_down(v, 4);  v += __shfl_down(v, 2);  v += __shfl_down(v, 1);
  const int t = threadIdx.x;
  __syncthreads();
  if ((t & 63) == 0) red[t >> 6] = v;
  __syncthreads();
  return red[0] + red[1] + red[2] + red[3];
}

// ================= weight transform -> int8 {-1,0,+1} =================
// Wt layout: [o][ (kh*3+kw)*512 + ci ]; wsc[o] = mean|w_std| * gain[o] * ALPHA
__global__ __launch_bounds__(256) void wker(const float* __restrict__ w,
                                            const float* __restrict__ gain,
                                            i8t* __restrict__ Wt,
                                            float* __restrict__ wsc) {
  __shared__ float sw[KSZ];
  __shared__ float red[4];
  const int o = blockIdx.x;
  const int t = threadIdx.x;
  const float* wo = w + (size_t)o * KSZ;

  float s = 0.f;
  for (int j = t; j < KSZ; j += 256) { float v = wo[j]; sw[j] = v; s += v; }
  const float mean = blocksum256(s, red) * (1.f / 4608.f);

  float s2 = 0.f;
  for (int j = t; j < KSZ; j += 256) { float d = sw[j] - mean; s2 += d * d; }
  const float var  = blocksum256(s2, red) * (1.f / 4608.f);
  const float stdv = sqrtf(var);
  const float scale = 1.0f / sqrtf(4608.0f);
  const float inv = scale / (stdv + 1e-5f);

  float sa = 0.f;
  for (int j = t; j < KSZ; j += 256) {
    float ws = (sw[j] - mean) * inv;
    sa += fabsf(ws);
    i8t u = ws > 0.f ? (i8t)1 : (ws < 0.f ? (i8t)-1 : (i8t)0);
    Wt[(size_t)o * KSZ + (size_t)(j % 9) * CH + (j / 9)] = u; // OIHW -> (kh,kw,ci)
  }
  const float sf = blocksum256(sa, red) * (1.f / 4608.f);
  if (t == 0) wsc[o] = sf * gain[o] * ALPHA_C;
}

// ================= input binarize + NCHW -> padded NHWC int8 =================
__global__ __launch_bounds__(256) void bker(const float* __restrict__ x,
                                            const float* __restrict__ mb0,
                                            i8t* __restrict__ P) {
  __shared__ float tile[64][57];
  const int pc = blockIdx.x;             // 14 pixel chunks of 56
  const int cc = blockIdx.y;             // 8 ci chunks of 64
  const int n  = blockIdx.z;
  const int p0 = pc * 56;
  const int ci0 = cc * 64;
  const int t = threadIdx.x;

  const float* xb = x + ((size_t)n * CH + ci0) * PIX + p0;
  for (int i = t; i < 64 * 56; i += 256) {
    int ci = i / 56, p = i - ci * 56;
    tile[ci][p] = xb[(size_t)ci * PIX + p];
  }
  __syncthreads();
  for (int i = t; i < 56 * 64; i += 256) {
    int p = i >> 6, ci = i & 63;
    float v = tile[ci][p] + mb0[ci0 + ci];           // BETA = 1.0
    i8t u = v > 0.f ? (i8t)1 : (v < 0.f ? (i8t)-1 : (i8t)0);
    int pg = p0 + p;
    int h = pg / 28, wq = pg - h * 28;
    P[(((size_t)n * HP + (h + 1)) * WP + (wq + 1)) * CH + ci0 + ci] = u;
  }
}

// ================= binary implicit-GEMM conv (i8 MFMA) + fused epilogue =================
// M=25088, N=512, K=4608. 128x128 tile, BK=128 (i8), double-buffered LDS,
// 2-phase prefetch: stage(kt+1) issued before compute(kt), one barrier/K-step.
__global__ __launch_bounds__(256) void gemm_bin(const i8t* __restrict__ P,
                                                const i8t* __restrict__ Wt,
                                                const float* __restrict__ wsc,
                                                const float* __restrict__ x,
                                                const float* __restrict__ mb1,
                                                const float* __restrict__ pa,
                                                const float* __restrict__ mb2,
                                                float* __restrict__ out) {
  __shared__ i8t As[2][128 * 128];   // 16 KB each buffer
  __shared__ i8t Bs[2][128 * 128];

  // bijective XCD swizzle: 784 = 98*8
  const int bid = blockIdx.x;
  const int swz = (bid & 7) * 98 + (bid >> 3);
  const int bm = swz >> 2, bn = swz & 3;
  const int m0 = bm * 128, o0 = bn * 128;

  const int t = threadIdx.x;
  const int lane = t & 63, wid = t >> 6;
  const int wr = wid >> 1, wc = wid & 1;

  // ---- staging: 8 chunks of 16B per 128B row; 4 row-groups per thread ----
  const int c8 = t & 7;
  const int rbase = t >> 3;                       // 0..31; row = it*32 + rbase
  const int swko = (c8 * 16) ^ ((rbase & 7) << 4); // pre-swizzled src offset (bytes==elems)

  size_t apix[4];
#pragma unroll
  for (int it = 0; it < 4; ++it) {
    int m = m0 + it * 32 + rbase;
    int n = m / PIX;
    int pix = m - n * PIX;
    int h = pix / 28, wq = pix - h * 28;
    apix[it] = (((size_t)n * HP + h) * WP + wq) * CH + swko;
  }
  const i8t* Bbase = Wt + (size_t)(o0 + rbase) * KSZ + swko;

  i32x4 acc[4][4] = {};

  auto stage = [&](int s, int kt) {
    const int pos = kt >> 2;                      // kh*3+kw
    const int kh = pos / 3, kw = pos - kh * 3;
    const size_t aoff = (size_t)(kh * WP + kw) * CH + (size_t)(kt & 3) * 128;
    const size_t boff = (size_t)kt * 128;         // fully contiguous K for B
#pragma unroll
    for (int it = 0; it < 4; ++it) {
      gload16(P + apix[it] + aoff, (char*)&As[s][0] + it * 4096 + wid * 1024);
      gload16(Bbase + (size_t)it * 32 * KSZ + boff, (char*)&Bs[s][0] + it * 4096 + wid * 1024);
    }
  };

  auto compute = [&](int s) {
    const int kq = lane >> 4;
    const int rl = lane & 15;
#pragma unroll
    for (int ks = 0; ks < 2; ++ks) {
      i32x4 a[4], b[4];
      const int kb = ks * 64 + kq * 16;           // byte offset within 128B row
#pragma unroll
      for (int mf = 0; mf < 4; ++mf) {
        int r = wr * 64 + mf * 16 + rl;
        a[mf] = *(const i32x4*)(&As[s][r * 128 + (kb ^ ((r & 7) << 4))]);
      }
#pragma unroll
      for (int nf = 0; nf < 4; ++nf) {
        int r = wc * 64 + nf * 16 + rl;
        b[nf] = *(const i32x4*)(&Bs[s][r * 128 + (kb ^ ((r & 7) << 4))]);
      }
#pragma unroll
      for (int mf = 0; mf < 4; ++mf)
#pragma unroll
        for (int nf = 0; nf < 4; ++nf)
          acc[mf][nf] = __builtin_amdgcn_mfma_i32_16x16x64_i8(a[mf], b[nf], acc[mf][nf], 0, 0, 0);
    }
  };

  // ---- 2-phase prefetch pipeline ----
  stage(0, 0);
  __syncthreads();                                 // drain prologue loads
  int cur = 0;
  for (int kt = 0; kt < NKT; ++kt) {
    if (kt + 1 < NKT) stage(cur ^ 1, kt + 1);      // loads in flight under MFMA
    compute(cur);
    __syncthreads();                               // vmcnt(0)+lgkmcnt(0)+barrier
    cur ^= 1;
  }

  // ---- fused epilogue: *wsc + residual + b1 -> PReLU -> + b2 ----
  const int ccol = lane & 15;
  const int rq4 = (lane >> 4) * 4;
#pragma unroll
  for (int nf = 0; nf < 4; ++nf) {
    const int o = o0 + wc * 64 + nf * 16 + ccol;
    const float wv = wsc[o];
    const float b1 = mb1[o];
    const float ap = pa[o];
    const float b2 = mb2[o];
#pragma unroll
    for (int mf = 0; mf < 4; ++mf) {
      const int m = m0 + wr * 64 + mf * 16 + rq4;
      const int n = m / PIX;
      const int pix = m - n * PIX;
      const size_t base = ((size_t)(n * CH + o)) * PIX + pix;  // NCHW fp32
      const float4 r = *reinterpret_cast<const float4*>(x + base);
      const float rv[4] = {r.x, r.y, r.z, r.w};
      float4 ov;
      float* po = &ov.x;
#pragma unroll
      for (int q = 0; q < 4; ++q) {
        float v = (float)acc[mf][nf][q] * wv + rv[q] + b1;
        v = v >= 0.f ? v : ap * v;
        po[q] = v + b2;
      }
      *reinterpret_cast<float4*>(out + base) = ov;
    }
  }
}

extern "C" void kernel_launch(void* const* d_in, const int* in_sizes, int n_in,
                              void* d_out, int out_size, void* d_ws, size_t ws_size,
                              hipStream_t stream) {
  const float* x    = (const float*)d_in[0];
  const float* mb0  = (const float*)d_in[1];
  const float* w    = (const float*)d_in[2];
  const float* gain = (const float*)d_in[3];
  const float* mb1  = (const float*)d_in[4];
  const float* pa   = (const float*)d_in[5];
  const float* mb2  = (const float*)d_in[6];
  float* out = (float*)d_out;

  char* ws = (char*)d_ws;
  const size_t P_BYTES  = (size_t)NIMG * HP * WP * CH;   // 14,745,600 (i8)
  const size_t WT_BYTES = (size_t)CH * KSZ;              //  2,359,296 (i8)
  i8t*   P  = (i8t*)ws;
  i8t*   Wt = (i8t*)(ws + P_BYTES);
  float* wv = (float*)(ws + P_BYTES + WT_BYTES);

  hipMemsetAsync(P, 0, P_BYTES, stream);                 // zero halo
  wker<<<512, 256, 0, stream>>>(w, gain, Wt, wv);
  bker<<<dim3(14, 8, NIMG), 256, 0, stream>>>(x, mb0, P);
  gemm_bin<<<784, 256, 0, stream>>>(P, Wt, wv, x, mb1, pa, mb2, out);
}

// Round 3
// 123.661 us; speedup vs baseline: 1.7787x; 1.1298x over previous
//
#include <hip/hip_runtime.h>
#include <stdint.h>

typedef unsigned short u16;
typedef signed char i8t;
typedef __attribute__((ext_vector_type(4))) int i32x4;

#define NIMG 32
#define CH   512         // Cin == Cout == 512
#define HP   30          // padded
#define WP   30
#define PIX  784         // 28*28
#define KSZ  4608        // 512*9
#define ALPHA_C 0.2f
#define NKT  36          // K tiles of 128 (i8)

// ---- async global->LDS, 16B per lane (LDS dest = wave-uniform base + lane*16) ----
__device__ __forceinline__ void gload16(const void* g, void* l) {
  __builtin_amdgcn_global_load_lds((const __attribute__((address_space(1))) void*)g,
                                   (__attribute__((address_space(3))) void*)l, 16, 0, 0);
}

// ---- block (256-thread) sum reduction ----
__device__ __forceinline__ float blocksum256(float v, float* red) {
  v += __shfl_down(v, 32); v += __shfl_down(v, 16); v += __shfl_down(v, 8);
  v += __shfl_down(v, 4);  v += __shfl_down(v, 2);  v += __shfl_down(v, 1);
  const int t = threadIdx.x;
  __syncthreads();
  if ((t & 63) == 0) red[t >> 6] = v;
  __syncthreads();
  return red[0] + red[1] + red[2] + red[3];
}

// ================= weight transform -> int8 {-1,0,+1} =================
__global__ __launch_bounds__(256) void wker(const float* __restrict__ w,
                                            const float* __restrict__ gain,
                                            i8t* __restrict__ Wt,
                                            float* __restrict__ wsc) {
  __shared__ float sw[KSZ];
  __shared__ float red[4];
  const int o = blockIdx.x;
  const int t = threadIdx.x;
  const float* wo = w + (size_t)o * KSZ;

  float s = 0.f;
  for (int j = t; j < KSZ; j += 256) { float v = wo[j]; sw[j] = v; s += v; }
  const float mean = blocksum256(s, red) * (1.f / 4608.f);

  float s2 = 0.f;
  for (int j = t; j < KSZ; j += 256) { float d = sw[j] - mean; s2 += d * d; }
  const float var  = blocksum256(s2, red) * (1.f / 4608.f);
  const float stdv = sqrtf(var);
  const float scale = 1.0f / sqrtf(4608.0f);
  const float inv = scale / (stdv + 1e-5f);

  float sa = 0.f;
  for (int j = t; j < KSZ; j += 256) {
    float ws = (sw[j] - mean) * inv;
    sa += fabsf(ws);
    i8t u = ws > 0.f ? (i8t)1 : (ws < 0.f ? (i8t)-1 : (i8t)0);
    Wt[(size_t)o * KSZ + (size_t)(j % 9) * CH + (j / 9)] = u; // OIHW -> (kh,kw,ci)
  }
  const float sf = blocksum256(sa, red) * (1.f / 4608.f);
  if (t == 0) wsc[o] = sf * gain[o] * ALPHA_C;
}

// ================= input binarize + NCHW -> padded NHWC int8 =================
__global__ __launch_bounds__(256) void bker(const float* __restrict__ x,
                                            const float* __restrict__ mb0,
                                            i8t* __restrict__ P) {
  __shared__ float tile[64][57];
  const int pc = blockIdx.x;             // 14 pixel chunks of 56
  const int cc = blockIdx.y;             // 8 ci chunks of 64
  const int n  = blockIdx.z;
  const int p0 = pc * 56;
  const int ci0 = cc * 64;
  const int t = threadIdx.x;

  const float* xb = x + ((size_t)n * CH + ci0) * PIX + p0;
  for (int i = t; i < 64 * 56; i += 256) {
    int ci = i / 56, p = i - ci * 56;
    tile[ci][p] = xb[(size_t)ci * PIX + p];
  }
  __syncthreads();
  for (int i = t; i < 56 * 64; i += 256) {
    int p = i >> 6, ci = i & 63;
    float v = tile[ci][p] + mb0[ci0 + ci];           // BETA = 1.0
    i8t u = v > 0.f ? (i8t)1 : (v < 0.f ? (i8t)-1 : (i8t)0);
    int pg = p0 + p;
    int h = pg / 28, wq = pg - h * 28;
    P[(((size_t)n * HP + (h + 1)) * WP + (wq + 1)) * CH + ci0 + ci] = u;
  }
}

// ================= binary implicit-GEMM conv (i8 MFMA) + fused epilogue =================
// M=25088, N=512, K=4608. 256x256 tile, BK=128, 8 waves (2x4), dbuf LDS 128KB,
// 2-deep prefetch with COUNTED vmcnt (never 0 in main loop), raw barriers.
__global__ __launch_bounds__(512, 2) void gemm_bin(const i8t* __restrict__ P,
                                                   const i8t* __restrict__ Wt,
                                                   const float* __restrict__ wsc,
                                                   const float* __restrict__ x,
                                                   const float* __restrict__ mb1,
                                                   const float* __restrict__ pa,
                                                   const float* __restrict__ mb2,
                                                   float* __restrict__ out) {
  __shared__ i8t As[2][256 * 128];   // 32 KB each
  __shared__ i8t Bs[2][256 * 128];

  // bijective XCD swizzle for grid 196 (q=24, r=4)  [m204]
  const int bid = blockIdx.x;
  const int xcd = bid & 7, idx = bid >> 3;
  const int swz = (xcd < 4 ? xcd * 25 : 100 + (xcd - 4) * 24) + idx;
  const int bm = swz >> 1, bn = swz & 1;
  const int m0 = bm * 256, o0 = bn * 256;

  const int t = threadIdx.x;
  const int lane = t & 63, wid = t >> 6;
  const int wr = wid >> 2, wc = wid & 3;            // 2x4 wave grid

  // ---- staging: 8 chunks of 16B per 128B row; 64 rows per round, 4 rounds ----
  const int c8 = t & 7;
  const int rbase = t >> 3;                         // 0..63; row = it*64 + rbase
  const int swko = (c8 * 16) ^ ((rbase & 7) << 4);  // pre-swizzled src byte offset

  size_t apix[4];
#pragma unroll
  for (int it = 0; it < 4; ++it) {
    int m = m0 + it * 64 + rbase;
    int n = m / PIX;
    int pix = m - n * PIX;
    int h = pix / 28, wq = pix - h * 28;
    apix[it] = (((size_t)n * HP + h) * WP + wq) * CH + swko;
  }
  const i8t* Bbase = Wt + (size_t)(o0 + rbase) * KSZ + swko;

  i32x4 acc[8][4] = {};

  auto stage = [&](int s, int kt) {
    const int pos = kt >> 2;                        // kh*3+kw
    const int kh = pos / 3, kw = pos - kh * 3;
    const size_t aoff = (size_t)(kh * WP + kw) * CH + (size_t)(kt & 3) * 128;
    const size_t boff = (size_t)kt * 128;
#pragma unroll
    for (int it = 0; it < 4; ++it) {
      gload16(P + apix[it] + aoff, (char*)&As[s][0] + it * 8192 + wid * 1024);
      gload16(Bbase + (size_t)it * 64 * KSZ + boff, (char*)&Bs[s][0] + it * 8192 + wid * 1024);
    }
  };

  auto compute = [&](int s) {
    const int kq = lane >> 4;
    const int rl = lane & 15;
#pragma unroll
    for (int ks = 0; ks < 2; ++ks) {
      i32x4 a[8], b[4];
      const int kb = ks * 64 + kq * 16;
#pragma unroll
      for (int mf = 0; mf < 8; ++mf) {
        int r = wr * 128 + mf * 16 + rl;
        a[mf] = *(const i32x4*)(&As[s][r * 128 + (kb ^ ((r & 7) << 4))]);
      }
#pragma unroll
      for (int nf = 0; nf < 4; ++nf) {
        int r = wc * 64 + nf * 16 + rl;
        b[nf] = *(const i32x4*)(&Bs[s][r * 128 + (kb ^ ((r & 7) << 4))]);
      }
      __builtin_amdgcn_s_setprio(1);
#pragma unroll
      for (int mf = 0; mf < 8; ++mf)
#pragma unroll
        for (int nf = 0; nf < 4; ++nf)
          acc[mf][nf] = __builtin_amdgcn_mfma_i32_16x16x64_i8(a[mf], b[nf], acc[mf][nf], 0, 0, 0);
      __builtin_amdgcn_s_setprio(0);
    }
  };

  // ---- 2-deep counted-vmcnt pipeline ----
  stage(0, 0);
  stage(1, 1);                                      // 16 loads/thread in flight
  int cur = 0;
  for (int kt = 0; kt < NKT - 2; ++kt) {
    // oldest 8 (buf cur) complete; newest 8 stay in flight across the barrier
    asm volatile("s_waitcnt vmcnt(8)\n\ts_barrier" ::: "memory");
    compute(cur);
    asm volatile("s_barrier" ::: "memory");         // all waves done reading buf cur
    stage(cur, kt + 2);                             // refill -> 16 in flight
    cur ^= 1;
  }
  // kt = NKT-2: 16 outstanding
  asm volatile("s_waitcnt vmcnt(8)\n\ts_barrier" ::: "memory");
  compute(cur);
  cur ^= 1;
  // kt = NKT-1: drain
  asm volatile("s_waitcnt vmcnt(0)\n\ts_barrier" ::: "memory");
  compute(cur);

  // ---- fused epilogue: *wsc + residual + b1 -> PReLU -> + b2 ----
  const int ccol = lane & 15;
  const int rq4 = (lane >> 4) * 4;
#pragma unroll
  for (int nf = 0; nf < 4; ++nf) {
    const int o = o0 + wc * 64 + nf * 16 + ccol;
    const float wv = wsc[o];
    const float b1 = mb1[o];
    const float ap = pa[o];
    const float b2 = mb2[o];
#pragma unroll
    for (int mf = 0; mf < 8; ++mf) {
      const int m = m0 + wr * 128 + mf * 16 + rq4;
      const int n = m / PIX;
      const int pix = m - n * PIX;
      const size_t base = ((size_t)(n * CH + o)) * PIX + pix;  // NCHW fp32
      const float4 r = *reinterpret_cast<const float4*>(x + base);
      const float rv[4] = {r.x, r.y, r.z, r.w};
      float4 ov;
      float* po = &ov.x;
#pragma unroll
      for (int q = 0; q < 4; ++q) {
        float v = (float)acc[mf][nf][q] * wv + rv[q] + b1;
        v = v >= 0.f ? v : ap * v;
        po[q] = v + b2;
      }
      *reinterpret_cast<float4*>(out + base) = ov;
    }
  }
}

extern "C" void kernel_launch(void* const* d_in, const int* in_sizes, int n_in,
                              void* d_out, int out_size, void* d_ws, size_t ws_size,
                              hipStream_t stream) {
  const float* x    = (const float*)d_in[0];
  const float* mb0  = (const float*)d_in[1];
  const float* w    = (const float*)d_in[2];
  const float* gain = (const float*)d_in[3];
  const float* mb1  = (const float*)d_in[4];
  const float* pa   = (const float*)d_in[5];
  const float* mb2  = (const float*)d_in[6];
  float* out = (float*)d_out;

  char* ws = (char*)d_ws;
  const size_t P_BYTES  = (size_t)NIMG * HP * WP * CH;   // 14,745,600 (i8)
  const size_t WT_BYTES = (size_t)CH * KSZ;              //  2,359,296 (i8)
  i8t*   P  = (i8t*)ws;
  i8t*   Wt = (i8t*)(ws + P_BYTES);
  float* wv = (float*)(ws + P_BYTES + WT_BYTES);

  hipMemsetAsync(P, 0, P_BYTES, stream);                 // zero halo
  wker<<<512, 256, 0, stream>>>(w, gain, Wt, wv);
  bker<<<dim3(14, 8, NIMG), 256, 0, stream>>>(x, mb0, P);
  gemm_bin<<<196, 512, 0, stream>>>(P, Wt, wv, x, mb1, pa, mb2, out);
}

// Round 4
// 119.493 us; speedup vs baseline: 1.8407x; 1.0349x over previous
//
#include <hip/hip_runtime.h>
#include <stdint.h>

typedef unsigned short u16;
typedef signed char i8t;
typedef __attribute__((ext_vector_type(4))) int i32x4;

#define NIMG 32
#define CH   512         // Cin == Cout == 512
#define HP   30          // padded
#define WP   30
#define PIX  784         // 28*28
#define KSZ  4608        // 512*9
#define ALPHA_C 0.2f
#define NKT  36          // K tiles of 128 (i8)

// ---- async global->LDS, 16B per lane (LDS dest = wave-uniform base + lane*16) ----
__device__ __forceinline__ void gload16(const void* g, void* l) {
  __builtin_amdgcn_global_load_lds((const __attribute__((address_space(1))) void*)g,
                                   (__attribute__((address_space(3))) void*)l, 16, 0, 0);
}

// ---- block (256-thread) sum reduction ----
__device__ __forceinline__ float blocksum256(float v, float* red) {
  v += __shfl_down(v, 32); v += __shfl_down(v, 16); v += __shfl_down(v, 8);
  v += __shfl_down(v, 4);  v += __shfl_down(v, 2);  v += __shfl_down(v, 1);
  const int t = threadIdx.x;
  __syncthreads();
  if ((t & 63) == 0) red[t >> 6] = v;
  __syncthreads();
  return red[0] + red[1] + red[2] + red[3];
}

// ================= weight transform -> int8 {-1,0,+1} =================
__global__ __launch_bounds__(256) void wker(const float* __restrict__ w,
                                            const float* __restrict__ gain,
                                            i8t* __restrict__ Wt,
                                            float* __restrict__ wsc) {
  __shared__ float sw[KSZ];
  __shared__ float red[4];
  const int o = blockIdx.x;
  const int t = threadIdx.x;
  const float* wo = w + (size_t)o * KSZ;

  float s = 0.f;
  for (int j = t; j < KSZ; j += 256) { float v = wo[j]; sw[j] = v; s += v; }
  const float mean = blocksum256(s, red) * (1.f / 4608.f);

  float s2 = 0.f;
  for (int j = t; j < KSZ; j += 256) { float d = sw[j] - mean; s2 += d * d; }
  const float var  = blocksum256(s2, red) * (1.f / 4608.f);
  const float stdv = sqrtf(var);
  const float scale = 1.0f / sqrtf(4608.0f);
  const float inv = scale / (stdv + 1e-5f);

  float sa = 0.f;
  for (int j = t; j < KSZ; j += 256) {
    float ws = (sw[j] - mean) * inv;
    sa += fabsf(ws);
    i8t u = ws > 0.f ? (i8t)1 : (ws < 0.f ? (i8t)-1 : (i8t)0);
    Wt[(size_t)o * KSZ + (size_t)(j % 9) * CH + (j / 9)] = u; // OIHW -> (kh,kw,ci)
  }
  const float sf = blocksum256(sa, red) * (1.f / 4608.f);
  if (t == 0) wsc[o] = sf * gain[o] * ALPHA_C;
}

// ================= input binarize + NCHW -> padded NHWC int8 (+halo zero) =================
__global__ __launch_bounds__(256) void bker(const float* __restrict__ x,
                                            const float* __restrict__ mb0,
                                            i8t* __restrict__ P) {
  __shared__ float tile[64][57];
  const int pc = blockIdx.x;             // 14 pixel chunks of 56
  const int cc = blockIdx.y;             // 8 ci chunks of 64
  const int n  = blockIdx.z;
  const int p0 = pc * 56;
  const int ci0 = cc * 64;
  const int t = threadIdx.x;

  // halo zeroing (replaces the memset): 116 border positions x 64 ci = 64B each
  if (pc == 0) {
    for (int i = t; i < 116 * 16; i += 256) {
      int pos = i >> 4, wq = i & 15;
      int hp, wp;
      if (pos < 30)      { hp = 0;        wp = pos; }
      else if (pos < 60) { hp = 29;       wp = pos - 30; }
      else if (pos < 88) { hp = pos - 59; wp = 0; }
      else               { hp = pos - 87; wp = 29; }
      uint32_t* dst = (uint32_t*)(P + (((size_t)n * HP + hp) * WP + wp) * CH + ci0);
      dst[wq] = 0u;
    }
  }

  const float* xb = x + ((size_t)n * CH + ci0) * PIX + p0;
  for (int i = t; i < 64 * 56; i += 256) {
    int ci = i / 56, p = i - ci * 56;
    tile[ci][p] = xb[(size_t)ci * PIX + p];
  }
  __syncthreads();
  for (int i = t; i < 56 * 64; i += 256) {
    int p = i >> 6, ci = i & 63;
    float v = tile[ci][p] + mb0[ci0 + ci];           // BETA = 1.0
    i8t u = v > 0.f ? (i8t)1 : (v < 0.f ? (i8t)-1 : (i8t)0);
    int pg = p0 + p;
    int h = pg / 28, wq = pg - h * 28;
    P[(((size_t)n * HP + (h + 1)) * WP + (wq + 1)) * CH + ci0 + ci] = u;
  }
}

// ================= binary implicit-GEMM conv (i8 MFMA) + fused epilogue =================
// M=25088, N=512, K=4608. 256x256 tile, BK=128, 8 waves (2x4), dbuf LDS 128KB.
// 8-phase m201-style schedule: per K-tile 4 phases, each {stage-issue || ds_read
// quadrant -> setprio+16 MFMA -> barrier}; prefetch kt+1 issued in phases 0-1.
__global__ __launch_bounds__(512, 2) void gemm_bin(const i8t* __restrict__ P,
                                                   const i8t* __restrict__ Wt,
                                                   const float* __restrict__ wsc,
                                                   const float* __restrict__ x,
                                                   const float* __restrict__ mb1,
                                                   const float* __restrict__ pa,
                                                   const float* __restrict__ mb2,
                                                   float* __restrict__ out) {
  __shared__ i8t As[2][256 * 128];   // 32 KB each
  __shared__ i8t Bs[2][256 * 128];

  // bijective XCD swizzle for grid 196 (q=24, r=4)  [m204]
  const int bid = blockIdx.x;
  const int xcd = bid & 7, idx = bid >> 3;
  const int swz = (xcd < 4 ? xcd * 25 : 100 + (xcd - 4) * 24) + idx;
  const int bm = swz >> 1, bn = swz & 1;
  const int m0 = bm * 256, o0 = bn * 256;

  const int t = threadIdx.x;
  const int lane = t & 63, wid = t >> 6;
  const int wr = wid >> 2, wc = wid & 3;            // 2x4 wave grid

  // ---- staging: 8 chunks of 16B per 128B row; 64 rows per round, 4 rounds ----
  const int c8 = t & 7;
  const int rbase = t >> 3;                         // 0..63; row = it*64 + rbase
  const int swko = (c8 * 16) ^ ((rbase & 7) << 4);  // pre-swizzled src byte offset

  size_t apix[4];
#pragma unroll
  for (int it = 0; it < 4; ++it) {
    int m = m0 + it * 64 + rbase;
    int n = m / PIX;
    int pix = m - n * PIX;
    int h = pix / 28, wq = pix - h * 28;
    apix[it] = (((size_t)n * HP + h) * WP + wq) * CH + swko;
  }
  const i8t* Bbase = Wt + (size_t)(o0 + rbase) * KSZ + swko;

  i32x4 acc[8][4] = {};

  // one A-gload + one B-gload of row-group `it` for tile kt into buffer s
  auto stage1 = [&](int s, int kt, int it) {
    const int pos = kt >> 2;                        // kh*3+kw
    const int kh = pos / 3, kw = pos - kh * 3;
    const size_t aoff = (size_t)(kh * WP + kw) * CH + (size_t)(kt & 3) * 128;
    const size_t boff = (size_t)kt * 128;
    gload16(P + apix[it] + aoff, (char*)&As[s][0] + it * 8192 + wid * 1024);
    gload16(Bbase + (size_t)it * 64 * KSZ + boff, (char*)&Bs[s][0] + it * 8192 + wid * 1024);
  };

  const int kq = lane >> 4, rl = lane & 15;

  auto ldA = [&](i32x4* a, int s, int ks, int mh) {
#pragma unroll
    for (int i = 0; i < 4; ++i) {
      int r = wr * 128 + (mh * 4 + i) * 16 + rl;
      int kb = ks * 64 + kq * 16;
      a[i] = *(const i32x4*)(&As[s][r * 128 + (kb ^ ((r & 7) << 4))]);
    }
  };
  auto ldB = [&](i32x4* b, int s, int ks) {
#pragma unroll
    for (int i = 0; i < 4; ++i) {
      int r = wc * 64 + i * 16 + rl;
      int kb = ks * 64 + kq * 16;
      b[i] = *(const i32x4*)(&Bs[s][r * 128 + (kb ^ ((r & 7) << 4))]);
    }
  };
  auto quad = [&](const i32x4* a, const i32x4* b, int mh) {
    __builtin_amdgcn_s_setprio(1);
#pragma unroll
    for (int i = 0; i < 4; ++i)
#pragma unroll
      for (int nf = 0; nf < 4; ++nf)
        acc[mh * 4 + i][nf] =
            __builtin_amdgcn_mfma_i32_16x16x64_i8(a[i], b[nf], acc[mh * 4 + i][nf], 0, 0, 0);
    __builtin_amdgcn_s_setprio(0);
    __builtin_amdgcn_sched_barrier(0);
  };

  // one K-tile = 4 phases; c is a literal at each call site (static LDS buffer)
  auto tile_body = [&](int c, int kt, bool pf) {
    i32x4 a[4], b0[4], b1[4];
    // ---- phase 0: (ks0, mh0) ----
    asm volatile("s_waitcnt vmcnt(0)\n\ts_barrier" ::: "memory");  // tile kt landed
    if (pf) { stage1(c ^ 1, kt + 1, 0); stage1(c ^ 1, kt + 1, 1); }
    ldB(b0, c, 0); ldA(a, c, 0, 0);
    quad(a, b0, 0);
    asm volatile("s_barrier" ::: "memory");
    // ---- phase 1: (ks0, mh1) ----
    if (pf) { stage1(c ^ 1, kt + 1, 2); stage1(c ^ 1, kt + 1, 3); }
    ldA(a, c, 0, 1);
    quad(a, b0, 1);
    asm volatile("s_barrier" ::: "memory");
    // ---- phase 2: (ks1, mh0) ----
    ldB(b1, c, 1); ldA(a, c, 1, 0);
    quad(a, b1, 0);
    asm volatile("s_barrier" ::: "memory");
    // ---- phase 3: (ks1, mh1) ----
    ldA(a, c, 1, 1);
    quad(a, b1, 1);
    asm volatile("s_barrier" ::: "memory");
  };

  // prologue: stage tile 0 fully into buf 0
#pragma unroll
  for (int it = 0; it < 4; ++it) stage1(0, 0, it);

  for (int kt = 0; kt < NKT; kt += 2) {             // 2 K-tiles/iter -> static bufs
    tile_body(0, kt, true);
    tile_body(1, kt + 1, kt + 2 < NKT);
  }

  // ---- fused epilogue: *wsc + residual + b1 -> PReLU -> + b2 ----
  const int ccol = lane & 15;
  const int rq4 = (lane >> 4) * 4;
#pragma unroll
  for (int nf = 0; nf < 4; ++nf) {
    const int o = o0 + wc * 64 + nf * 16 + ccol;
    const float wv = wsc[o];
    const float b1 = mb1[o];
    const float ap = pa[o];
    const float b2 = mb2[o];
#pragma unroll
    for (int mf = 0; mf < 8; ++mf) {
      const int m = m0 + wr * 128 + mf * 16 + rq4;
      const int n = m / PIX;
      const int pix = m - n * PIX;
      const size_t base = ((size_t)(n * CH + o)) * PIX + pix;  // NCHW fp32
      const float4 r = *reinterpret_cast<const float4*>(x + base);
      const float rv[4] = {r.x, r.y, r.z, r.w};
      float4 ov;
      float* po = &ov.x;
#pragma unroll
      for (int q = 0; q < 4; ++q) {
        float v = (float)acc[mf][nf][q] * wv + rv[q] + b1;
        v = v >= 0.f ? v : ap * v;
        po[q] = v + b2;
      }
      *reinterpret_cast<float4*>(out + base) = ov;
    }
  }
}

extern "C" void kernel_launch(void* const* d_in, const int* in_sizes, int n_in,
                              void* d_out, int out_size, void* d_ws, size_t ws_size,
                              hipStream_t stream) {
  const float* x    = (const float*)d_in[0];
  const float* mb0  = (const float*)d_in[1];
  const float* w    = (const float*)d_in[2];
  const float* gain = (const float*)d_in[3];
  const float* mb1  = (const float*)d_in[4];
  const float* pa   = (const float*)d_in[5];
  const float* mb2  = (const float*)d_in[6];
  float* out = (float*)d_out;

  char* ws = (char*)d_ws;
  const size_t P_BYTES  = (size_t)NIMG * HP * WP * CH;   // 14,745,600 (i8)
  const size_t WT_BYTES = (size_t)CH * KSZ;              //  2,359,296 (i8)
  i8t*   P  = (i8t*)ws;
  i8t*   Wt = (i8t*)(ws + P_BYTES);
  float* wv = (float*)(ws + P_BYTES + WT_BYTES);

  wker<<<512, 256, 0, stream>>>(w, gain, Wt, wv);
  bker<<<dim3(14, 8, NIMG), 256, 0, stream>>>(x, mb0, P);   // also zeroes halo
  gemm_bin<<<196, 512, 0, stream>>>(P, Wt, wv, x, mb1, pa, mb2, out);
}